// Round 17
// baseline (3247.171 us; speedup 1.0000x reference)
//
#include <hip/hip_runtime.h>

namespace {

typedef _Float16 __attribute__((ext_vector_type(2))) h2v;   // one VGPR = 2 f16

constexpr int KST = 1024;
constexpr size_t OFF_R = (size_t)512 * KST * 5;
constexpr size_t OFF_D = OFF_R + (size_t)512 * KST * 8;

__device__ __forceinline__ float sigf(float x) { return 1.0f / (1.0f + __expf(-x)); }
__device__ __forceinline__ float tanhfast(float x) {
    float e2 = __expf(2.0f * x);
    return 1.0f - 2.0f / (e2 + 1.0f);
}
__device__ __forceinline__ float fdot2(h2v a, h2v b, float c) {
    return __builtin_amdgcn_fdot2(a, b, c, false);
}

// v17 = v16 (best: 3149us) with ONE change: all out[] global stores are moved
// OFF the critical wave. __syncthreads compiles to s_waitcnt vmcnt(0) before
// s_barrier, so wave 0's y-stores (issued ~100cyc before the Psi2 barrier,
// ~300-500cyc store latency) put ~200-400cyc of drain on the critical path
// EVERY step. Now: wave 0 stages results in double-buffered LDS (sOutR/sOutY,
// parity k&1); wave 1 — which idles ~700cyc at the Psi2 barrier waiting for
// wave 0's tail — issues the step-(k-1) global stores at the top of Psi2,
// its drain absorbed by that slack. Epilogue flushes step K-1. Values are
// byte-identical to v16.
__global__ __launch_bounds__(768, 3) void rnn_v17(
    const float* __restrict__ y0,     const float* __restrict__ u_seq,
    const float* __restrict__ dt_seq, const float* __restrict__ W_lift,
    const float* __restrict__ b_lift, const float* __restrict__ W_ih,
    const float* __restrict__ W_hh,   const float* __restrict__ b_ih,
    const float* __restrict__ b_hh,   const float* __restrict__ W_head,
    const float* __restrict__ b_head, const float* __restrict__ u2y,
    float* __restrict__ out)
{
    const int t    = threadIdx.x;        // 0..767
    const int lane = t & 63;
    const int wid  = t >> 6;
    const int hf   = (t >= 384) ? 1 : 0; // column half (wave-uniform)
    const int o    = t - hf * 384;       // owned GRU output row 0..383
    const int b0   = blockIdx.x * 2;     // two batch rows per WG
    const int rh   = (lane >> 4) & 1;    // head/RK4 home row for this lane
    const int ri   = lane & 15;          // home state index (junk >4)

    // M^10 lane constants (25 active lanes per batch row)
    const int mr = (lane >= 32) ? 1 : 0;   // batch row served
    const int me = lane - mr * 32;         // entry id (>=25 junk)
    const int mi = me / 5;                 // matrix row (junk >4)
    const int mj = me - mi * 5;            // matrix col 0..4
    const int rowBase = mr * 32 + mi * 5;
    const int colBase = mr * 32 + mj;

    __shared__ alignas(16) float sWlift[64 * 9];
    __shared__ float sblift[64];
    __shared__ alignas(16) float sWheadP[13 * 132];      // padded stride 132
    __shared__ float sbhead[16];
    __shared__ float sU2Y[20];                           // u2y row-major (U,P)
    __shared__ alignas(16) _Float16 sX2hi[2][64];        // x high f16
    __shared__ alignas(16) _Float16 sX2lo[2][64];        // x residual f16
    __shared__ alignas(16) _Float16 sWihLo[2][384][36];  // W_ih f16 residuals (72B stride)
    __shared__ alignas(16) float sH[2][128];             // h fp32 (head consumer)
    __shared__ alignas(16) _Float16 sH2[2][128];         // h f16 (gh consumer)
    __shared__ alignas(16) float sGiP[2][2][384];        // [half][row][out]
    __shared__ alignas(16) float sGhP[2][2][384];
    __shared__ alignas(16) float sOutR[2][2][16];        // [buf][row][rates8+dhid5]
    __shared__ alignas(16) float sOutY[2][2][8];         // [buf][row][y5]

    // ---- f16-packed per-thread hi weight rows (48 VGPRs) ----
    h2v wih2[16];   // W_ih[o][hf*32 .. +31] (hi)
    h2v whh2[32];   // W_hh[o][hf*64 .. +63] (hi)
    {
        const float* p = W_ih + (size_t)o * 64 + hf * 32;
#pragma unroll
        for (int i = 0; i < 16; i++)
            wih2[i] = h2v{(_Float16)p[2 * i], (_Float16)p[2 * i + 1]};
        const float* q = W_hh + (size_t)o * 128 + hf * 64;
#pragma unroll
        for (int i = 0; i < 32; i++)
            whh2[i] = h2v{(_Float16)q[2 * i], (_Float16)q[2 * i + 1]};
    }
    const float bihv = hf ? 0.0f : b_ih[o];
    const float bhhv = hf ? 0.0f : b_hh[o];
#pragma unroll
    for (int i = 0; i < 16; i++) asm volatile("" : "+v"(wih2[i]));
#pragma unroll
    for (int i = 0; i < 32; i++) asm volatile("" : "+v"(whh2[i]));

    // ---- cooperative LDS init ----
    for (int i = t; i < 576; i += 768) sWlift[i] = W_lift[i];
    if (t < 64) sblift[t] = b_lift[t];
    for (int i = t; i < 13 * 128; i += 768) {
        int oo = i >> 7, c = i & 127;
        sWheadP[oo * 132 + c] = W_head[i];
    }
    for (int i = t; i < 2 * 384 * 32; i += 768) {   // W_ih residuals
        int hh = i / (384 * 32);
        int rem = i - hh * 384 * 32;
        int oo = rem >> 5, c = rem & 31;
        float w = W_ih[(size_t)oo * 64 + hh * 32 + c];
        _Float16 wh = (_Float16)w;
        sWihLo[hh][oo][c] = (_Float16)(w - (float)wh);
    }
    if (t < 13) sbhead[t] = b_head[t];
    if (t < 20) sU2Y[t] = u2y[t];
    if (t < 256) {
        sH[t >> 7][t & 127] = 0.0f;
        sH2[t >> 7][t & 127] = (_Float16)0.0f;
    }
    sGhP[hf][0][o] = bhhv;   // gh(0) = b_hh (h0 = 0)
    sGhP[hf][1][o] = bhhv;

    // ---- wave-0 persistent y state (home layout: lane rh*16+i, i<5) ----
    float yreg = 0.0f;
    if (wid == 0)
        yreg = y0[(b0 + rh) * 5 + ((ri < 5) ? ri : 0)] + 0.01f;
    __syncthreads();

    auto do_gi = [&]() {   // gi = Whi*xhi + Whi*xlo + Wlo*xhi  (exact v11 order)
        float g0 = bihv, g1 = 0.0f;
        const h2v* xh0 = (const h2v*)&sX2hi[0][hf * 32];
        const h2v* xh1 = (const h2v*)&sX2hi[1][hf * 32];
        const h2v* xl0 = (const h2v*)&sX2lo[0][hf * 32];
        const h2v* xl1 = (const h2v*)&sX2lo[1][hf * 32];
        const h2v* wlo = (const h2v*)&sWihLo[hf][o][0];
#pragma unroll
        for (int i = 0; i < 16; i++) {
            h2v wl = wlo[i];
            g0 = fdot2(wih2[i], xh0[i], g0);
            g0 = fdot2(wih2[i], xl0[i], g0);
            g0 = fdot2(wl, xh0[i], g0);
            g1 = fdot2(wih2[i], xh1[i], g1);
            g1 = fdot2(wih2[i], xl1[i], g1);
            g1 = fdot2(wl, xh1[i], g1);
        }
        sGiP[hf][0][o] = g0;
        sGiP[hf][1][o] = g1;
    };
    auto do_gh = [&]() {
        float g0 = bhhv, g1 = 0.0f;
        const h2v* h0p = (const h2v*)&sH2[0][hf * 64];
        const h2v* h1p = (const h2v*)&sH2[1][hf * 64];
#pragma unroll
        for (int i = 0; i < 32; i++) {
            g0 = fdot2(whh2[i], h0p[i], g0);
            g1 = fdot2(whh2[i], h1p[i], g1);
        }
        sGhP[hf][0][o] = g0;
        sGhP[hf][1][o] = g1;
    };
    // wave 0; lane = x-output index; y delivered via in-wave shfl broadcast
    auto do_lift = [&](float4 u0, float4 u1, float yr) {
        float y00 = __shfl(yr, 0),  y01 = __shfl(yr, 1),  y02 = __shfl(yr, 2);
        float y03 = __shfl(yr, 3),  y04 = __shfl(yr, 4);
        float y10 = __shfl(yr, 16), y11 = __shfl(yr, 17), y12 = __shfl(yr, 18);
        float y13 = __shfl(yr, 19), y14 = __shfl(yr, 20);
        const float* wl = &sWlift[lane * 9];
        float bl = sblift[lane];
        float a0 = bl, a1 = bl;
        a0 = fmaf(wl[0], u0.x, a0);   a1 = fmaf(wl[0], u1.x, a1);
        a0 = fmaf(wl[1], u0.y, a0);   a1 = fmaf(wl[1], u1.y, a1);
        a0 = fmaf(wl[2], u0.z, a0);   a1 = fmaf(wl[2], u1.z, a1);
        a0 = fmaf(wl[3], u0.w, a0);   a1 = fmaf(wl[3], u1.w, a1);
        a0 = fmaf(wl[4], y00, a0);    a1 = fmaf(wl[4], y10, a1);
        a0 = fmaf(wl[5], y01, a0);    a1 = fmaf(wl[5], y11, a1);
        a0 = fmaf(wl[6], y02, a0);    a1 = fmaf(wl[6], y12, a1);
        a0 = fmaf(wl[7], y03, a0);    a1 = fmaf(wl[7], y13, a1);
        a0 = fmaf(wl[8], y04, a0);    a1 = fmaf(wl[8], y14, a1);
        float x0 = a0 * sigf(a0), x1 = a1 * sigf(a1);   // silu fp32
        _Float16 xh0 = (_Float16)x0;
        sX2hi[0][lane] = xh0;
        sX2lo[0][lane] = (_Float16)(x0 - (float)xh0);
        _Float16 xh1 = (_Float16)x1;
        sX2hi[1][lane] = xh1;
        sX2lo[1][lane] = (_Float16)(x1 - (float)xh1);
    };
    // slack-wave global store of step kp's staged results (wave 1)
    auto flush_out = [&](int kp) {
        int pb = kp & 1;
        if (lane < 36) {
            int row = (lane >= 18) ? 1 : 0;
            int idx = lane - row * 18;
            if (idx < 13) {
                float v = sOutR[pb][row][idx];
                if (idx < 8)
                    out[OFF_R + ((size_t)(b0 + row) * KST + kp) * 8 + idx] = v;
                else
                    out[OFF_D + ((size_t)(b0 + row) * KST + kp) * 5 + (idx - 8)] = v;
            } else {
                float v = sOutY[pb][row][idx - 13];
                out[((size_t)(b0 + row) * KST + kp) * 5 + (idx - 13)] = v;
            }
        }
    };

    // ---- prologue: lift(0), gi(0) ----
    if (wid == 0) {
        float4 u0 = *(const float4*)&u_seq[((size_t)b0 * KST) * 4];
        float4 u1 = *(const float4*)&u_seq[((size_t)(b0 + 1) * KST) * 4];
        do_lift(u0, u1, yreg);
    }
    __syncthreads();
    do_gi();
    __syncthreads();

    for (int k = 0; k < KST; k++) {
        // ---------- Ψ1: gates(k) ----------
        if (t < 256) {
            int r = t >> 7, q = t & 127;
            float ir  = sGiP[0][r][q]       + sGiP[1][r][q];
            float iz  = sGiP[0][r][q + 128] + sGiP[1][r][q + 128];
            float in_ = sGiP[0][r][q + 256] + sGiP[1][r][q + 256];
            float hr  = sGhP[0][r][q]       + sGhP[1][r][q];
            float hz  = sGhP[0][r][q + 128] + sGhP[1][r][q + 128];
            float hn  = sGhP[0][r][q + 256] + sGhP[1][r][q + 256];
            float rr = sigf(ir + hr);
            float z  = sigf(iz + hz);
            float n  = tanhfast(fmaf(rr, hn, in_));
            float h  = sH[r][q];
            float hnew = fmaf(z, h - n, n);
            sH[r][q] = hnew;
            sH2[r][q] = (_Float16)hnew;
        }
        __syncthreads();

        // ---------- Ψ2: wave1 flushes step k-1; gh(k+1) all; wave0 tail ----------
        float4 ukr{}, un0{}, un1{};
        float dtr = 0.0f;
        if (wid == 0) {   // early global loads (L2-resident); latency hides under gh
            int kn = (k + 1 < KST) ? k + 1 : KST - 1;
            ukr = *(const float4*)&u_seq[((size_t)(b0 + rh) * KST + k) * 4];
            dtr = dt_seq[(size_t)(b0 + rh) * KST + k];
            un0 = *(const float4*)&u_seq[((size_t)b0 * KST + kn) * 4];
            un1 = *(const float4*)&u_seq[((size_t)(b0 + 1) * KST + kn) * 4];
        }
        if (wid == 1 && k > 0) flush_out(k - 1);   // drain absorbed by barrier slack
        do_gh();
        if (wid == 0) {
            // ----- head: lane = hh*32 + rh*16 + oo; exact v11 summation tree -----
            const int hh = (lane >> 5) & 1;
            const int oo = lane & 15;
            float accv[4] = {0.f, 0.f, 0.f, 0.f};
            if (oo < 13) {
                const float4* wv = (const float4*)&sWheadP[oo * 132 + hh * 64];
                const float4* hv = (const float4*)&sH[rh][hh * 64];
#pragma unroll
                for (int c = 0; c < 4; c++) {
                    float4 w0 = wv[4 * c], w1 = wv[4 * c + 1], w2 = wv[4 * c + 2], w3 = wv[4 * c + 3];
                    float4 h0 = hv[4 * c], h1 = hv[4 * c + 1], h2 = hv[4 * c + 2], h3 = hv[4 * c + 3];
                    float a0 = w0.x * h0.x, a1 = w2.x * h2.x;
                    a0 = fmaf(w0.y, h0.y, a0); a1 = fmaf(w2.y, h2.y, a1);
                    a0 = fmaf(w0.z, h0.z, a0); a1 = fmaf(w2.z, h2.z, a1);
                    a0 = fmaf(w0.w, h0.w, a0); a1 = fmaf(w2.w, h2.w, a1);
                    a0 = fmaf(w1.x, h1.x, a0); a1 = fmaf(w3.x, h3.x, a1);
                    a0 = fmaf(w1.y, h1.y, a0); a1 = fmaf(w3.y, h3.y, a1);
                    a0 = fmaf(w1.z, h1.z, a0); a1 = fmaf(w3.z, h3.z, a1);
                    a0 = fmaf(w1.w, h1.w, a0); a1 = fmaf(w3.w, h3.w, a1);
                    accv[c] = a0 + a1;
                }
            }
            float p1 = accv[0] + accv[1];
            float p2 = accv[2] + accv[3];
            float part = p1 + p2;                       // ((s0+s1)+(s2+s3))
            float tot = part + __shfl_xor(part, 32);    // + ((s4+s5)+(s6+s7))
            float gval = 0.0f;
            if (oo < 13 && hh == 0) {
                float raw = tot + sbhead[oo];
                if (oo < 8) gval = fmaf(2.99f, sigf(raw), 0.01f);
                else        gval = 3.0f * sigf(raw);
                sOutR[k & 1][rh][oo] = gval;            // staged; wave 1 stores @k+1
            }

            // ----- y_jump on M lanes (all data via in-wave shfl) -----
            float u0x = __shfl(ukr.x, mr * 16), u0y = __shfl(ukr.y, mr * 16);
            float u0z = __shfl(ukr.z, mr * 16), u0w = __shfl(ukr.w, mr * 16);
            float dtv = __shfl(dtr, mr * 16);
            float dhj = __shfl(gval, mr * 16 + 8 + mj);
            float yj  = __shfl(yreg, mr * 16 + mj);
            float jmp = u0x * sU2Y[mj];
            jmp = fmaf(u0y, sU2Y[5 + mj], jmp);
            jmp = fmaf(u0z, sU2Y[10 + mj], jmp);
            jmp = fmaf(u0w, sU2Y[15 + mj], jmp);
            float yjv = yj + jmp + dhj;

            // ----- build M (one RK4 substep, exact; v12-proven) -----
            float kf1 = __shfl(gval, mr * 16 + 0);
            float kf2 = __shfl(gval, mr * 16 + 1);
            float kf3 = __shfl(gval, mr * 16 + 2);
            float kf4 = __shfl(gval, mr * 16 + 3);
            float kr1 = __shfl(gval, mr * 16 + 4);
            float kr2 = __shfl(gval, mr * 16 + 5);
            float kr3 = __shfl(gval, mr * 16 + 6);
            float kr4 = __shfl(gval, mr * 16 + 7);
            const float hstep = dtv * 0.1f;
            const float d1 = kr1 + kf2, d2 = kr2 + kf3, d3 = kr3 + kf4;
            float v0 = (mj == 0) ? 1.f : 0.f;
            float v1 = (mj == 1) ? 1.f : 0.f;
            float v2 = (mj == 2) ? 1.f : 0.f;
            float v3 = (mj == 3) ? 1.f : 0.f;
            float v4 = (mj == 4) ? 1.f : 0.f;
            float a0 = v0, a1 = v1, a2 = v2, a3 = v3, a4 = v4;
#pragma unroll
            for (int s = 1; s <= 4; s++) {
                const float hsf = hstep * ((s == 1) ? 1.0f : (s == 2) ? 0.5f
                                          : (s == 3) ? (1.0f / 3.0f) : 0.25f);
                float t0 = kr1 * v1 - kf1 * v0;
                float t1 = fmaf(kf1, v0, fmaf(kr2, v2, -d1 * v1));
                float t2 = fmaf(kf2, v1, fmaf(kr3, v3, -d2 * v2));
                float t3 = fmaf(kf3, v2, fmaf(kr4, v4, -d3 * v3));
                float t4 = kf4 * v3 - kr4 * v4;
                v0 = t0 * hsf; v1 = t1 * hsf; v2 = t2 * hsf; v3 = t3 * hsf; v4 = t4 * hsf;
                a0 += v0; a1 += v1; a2 += v2; a3 += v3; a4 += v4;
            }
            float m = a0;
            m = (mi == 1) ? a1 : m;
            m = (mi == 2) ? a2 : m;
            m = (mi == 3) ? a3 : m;
            m = (mi == 4) ? a4 : m;

            // ----- M^10 = ((M^2)^2 * M)^2 via lane-parallel 5x5 matmuls -----
            auto matmul = [&](float A, float B) -> float {
                float c = 0.0f;
#pragma unroll
                for (int kk = 0; kk < 5; kk++) {
                    float av = __shfl(A, rowBase + kk);
                    float bv = __shfl(B, colBase + 5 * kk);
                    c = fmaf(av, bv, c);
                }
                return c;
            };
            float m2  = matmul(m, m);
            float m4  = matmul(m2, m2);
            float m5  = matmul(m4, m);
            float m10 = matmul(m5, m5);

            // ----- y_out = M^10 * y_jump; clamp (no-op) kept for safety -----
            float p = m10 * yjv;
            float sum = __shfl(p, rowBase + 0);
            sum += __shfl(p, rowBase + 1);
            sum += __shfl(p, rowBase + 2);
            sum += __shfl(p, rowBase + 3);
            sum += __shfl(p, rowBase + 4);
            float ynew = fmaxf(sum, 0.0f);

            // scatter back to home layout (lane rh*16+i <- lane rh*32+i*5)
            yreg = __shfl(ynew, rh * 32 + ri * 5);
            if (lane < 32 && ri < 5)
                sOutY[k & 1][rh][ri] = yreg;             // staged; wave 1 stores @k+1
            do_lift(un0, un1, yreg);                     // lift(k+1), y via shfl
        }
        __syncthreads();

        // ---------- Ψ3: gi(k+1) ----------
        do_gi();
        __syncthreads();
    }

    // ---- epilogue: flush step KST-1 (staged in buffer (KST-1)&1) ----
    if (wid == 1) flush_out(KST - 1);
}

}  // namespace

extern "C" void kernel_launch(void* const* d_in, const int* in_sizes, int n_in,
                              void* d_out, int out_size, void* d_ws, size_t ws_size,
                              hipStream_t stream) {
    const float* y0     = (const float*)d_in[0];
    const float* u_seq  = (const float*)d_in[1];
    const float* dt_seq = (const float*)d_in[2];
    const float* W_lift = (const float*)d_in[3];
    const float* b_lift = (const float*)d_in[4];
    const float* W_ih   = (const float*)d_in[5];
    const float* W_hh   = (const float*)d_in[6];
    const float* b_ih   = (const float*)d_in[7];
    const float* b_hh   = (const float*)d_in[8];
    const float* W_head = (const float*)d_in[9];
    const float* b_head = (const float*)d_in[10];
    const float* u2y    = (const float*)d_in[11];
    float* out = (float*)d_out;

    rnn_v17<<<256, 768, 0, stream>>>(y0, u_seq, dt_seq, W_lift, b_lift,
                                     W_ih, W_hh, b_ih, b_hh, W_head, b_head,
                                     u2y, out);
}

// Round 18
// 3137.889 us; speedup vs baseline: 1.0348x; 1.0348x over previous
//
#include <hip/hip_runtime.h>

namespace {

typedef _Float16 __attribute__((ext_vector_type(2))) h2v;   // one VGPR = 2 f16

constexpr int KST = 1024;
constexpr size_t OFF_R = (size_t)512 * KST * 5;
constexpr size_t OFF_D = OFF_R + (size_t)512 * KST * 8;

__device__ __forceinline__ float sigf(float x) { return 1.0f / (1.0f + __expf(-x)); }
__device__ __forceinline__ float tanhfast(float x) {
    float e2 = __expf(2.0f * x);
    return 1.0f - 2.0f / (e2 + 1.0f);
}
__device__ __forceinline__ float fdot2(h2v a, h2v b, float c) {
    return __builtin_amdgcn_fdot2(a, b, c, false);
}

// FINAL (v18 = v16, best measured: 3149us, absmax 32 = bf16 output floor).
// Session summary of load-bearing decisions:
//  - Register-budget law (r1-r6): compiler budget = 256 / waves-per-SIMD;
//    768-thread WG -> 84 VGPRs, immovable. Weights must FIT: f16-packed hi
//    rows (48 regs) + fdot2 fp32-accumulate, pinned via asm.
//  - Accuracy (r7-r10): gate-error trajectory-flip threshold ~0.02; the
//    Wih_lo*x term (x up to O(1e3)) must be kept -> 3-term gi with W_ih f16
//    residuals in LDS. All error terms <=1e-4.
//  - Schedule (v11/v15/v16): 3 barriers/step; wave-0 serial tail (head ->
//    M^10 RK4 -> lift) hidden under waves 1-11's gh; y lives in wave-0 regs.
//  - M^10: one RK4 substep of the linear chain ODE is exactly
//    I + hB + (hB)^2/2 + (hB)^3/6 + (hB)^4/24; 10 substeps = M^10 via
//    square-and-multiply on 25 lanes/row; per-substep clamp is a no-op.
//  - Closed dead-ends: MFMA (latency-bound op), 2-WG co-residency (256-reg
//    /SIMD schedulable pool), store-offload (v17: lgkmcnt drain just moves).
__global__ __launch_bounds__(768, 3) void rnn_v18(
    const float* __restrict__ y0,     const float* __restrict__ u_seq,
    const float* __restrict__ dt_seq, const float* __restrict__ W_lift,
    const float* __restrict__ b_lift, const float* __restrict__ W_ih,
    const float* __restrict__ W_hh,   const float* __restrict__ b_ih,
    const float* __restrict__ b_hh,   const float* __restrict__ W_head,
    const float* __restrict__ b_head, const float* __restrict__ u2y,
    float* __restrict__ out)
{
    const int t    = threadIdx.x;        // 0..767
    const int lane = t & 63;
    const int wid  = t >> 6;
    const int hf   = (t >= 384) ? 1 : 0; // column half (wave-uniform)
    const int o    = t - hf * 384;       // owned GRU output row 0..383
    const int b0   = blockIdx.x * 2;     // two batch rows per WG
    const int rh   = (lane >> 4) & 1;    // head/RK4 home row for this lane
    const int ri   = lane & 15;          // home state index (junk >4)

    // M^10 lane constants (25 active lanes per batch row)
    const int mr = (lane >= 32) ? 1 : 0;   // batch row served
    const int me = lane - mr * 32;         // entry id (>=25 junk)
    const int mi = me / 5;                 // matrix row (junk >4)
    const int mj = me - mi * 5;            // matrix col 0..4
    const int rowBase = mr * 32 + mi * 5;
    const int colBase = mr * 32 + mj;

    __shared__ alignas(16) float sWlift[64 * 9];
    __shared__ float sblift[64];
    __shared__ alignas(16) float sWheadP[13 * 132];      // padded stride 132
    __shared__ float sbhead[16];
    __shared__ float sU2Y[20];                           // u2y row-major (U,P)
    __shared__ alignas(16) _Float16 sX2hi[2][64];        // x high f16
    __shared__ alignas(16) _Float16 sX2lo[2][64];        // x residual f16
    __shared__ alignas(16) _Float16 sWihLo[2][384][36];  // W_ih f16 residuals (72B stride)
    __shared__ alignas(16) float sH[2][128];             // h fp32 (head consumer)
    __shared__ alignas(16) _Float16 sH2[2][128];         // h f16 (gh consumer)
    __shared__ alignas(16) float sGiP[2][2][384];        // [half][row][out]
    __shared__ alignas(16) float sGhP[2][2][384];

    // ---- f16-packed per-thread hi weight rows (48 VGPRs) ----
    h2v wih2[16];   // W_ih[o][hf*32 .. +31] (hi)
    h2v whh2[32];   // W_hh[o][hf*64 .. +63] (hi)
    {
        const float* p = W_ih + (size_t)o * 64 + hf * 32;
#pragma unroll
        for (int i = 0; i < 16; i++)
            wih2[i] = h2v{(_Float16)p[2 * i], (_Float16)p[2 * i + 1]};
        const float* q = W_hh + (size_t)o * 128 + hf * 64;
#pragma unroll
        for (int i = 0; i < 32; i++)
            whh2[i] = h2v{(_Float16)q[2 * i], (_Float16)q[2 * i + 1]};
    }
    const float bihv = hf ? 0.0f : b_ih[o];
    const float bhhv = hf ? 0.0f : b_hh[o];
#pragma unroll
    for (int i = 0; i < 16; i++) asm volatile("" : "+v"(wih2[i]));
#pragma unroll
    for (int i = 0; i < 32; i++) asm volatile("" : "+v"(whh2[i]));

    // ---- cooperative LDS init ----
    for (int i = t; i < 576; i += 768) sWlift[i] = W_lift[i];
    if (t < 64) sblift[t] = b_lift[t];
    for (int i = t; i < 13 * 128; i += 768) {
        int oo = i >> 7, c = i & 127;
        sWheadP[oo * 132 + c] = W_head[i];
    }
    for (int i = t; i < 2 * 384 * 32; i += 768) {   // W_ih residuals
        int hh = i / (384 * 32);
        int rem = i - hh * 384 * 32;
        int oo = rem >> 5, c = rem & 31;
        float w = W_ih[(size_t)oo * 64 + hh * 32 + c];
        _Float16 wh = (_Float16)w;
        sWihLo[hh][oo][c] = (_Float16)(w - (float)wh);
    }
    if (t < 13) sbhead[t] = b_head[t];
    if (t < 20) sU2Y[t] = u2y[t];
    if (t < 256) {
        sH[t >> 7][t & 127] = 0.0f;
        sH2[t >> 7][t & 127] = (_Float16)0.0f;
    }
    sGhP[hf][0][o] = bhhv;   // gh(0) = b_hh (h0 = 0)
    sGhP[hf][1][o] = bhhv;

    // ---- wave-0 persistent y state (home layout: lane rh*16+i, i<5) ----
    float yreg = 0.0f;
    if (wid == 0)
        yreg = y0[(b0 + rh) * 5 + ((ri < 5) ? ri : 0)] + 0.01f;
    __syncthreads();

    auto do_gi = [&]() {   // gi = Whi*xhi + Whi*xlo + Wlo*xhi  (exact v11 order)
        float g0 = bihv, g1 = 0.0f;
        const h2v* xh0 = (const h2v*)&sX2hi[0][hf * 32];
        const h2v* xh1 = (const h2v*)&sX2hi[1][hf * 32];
        const h2v* xl0 = (const h2v*)&sX2lo[0][hf * 32];
        const h2v* xl1 = (const h2v*)&sX2lo[1][hf * 32];
        const h2v* wlo = (const h2v*)&sWihLo[hf][o][0];
#pragma unroll
        for (int i = 0; i < 16; i++) {
            h2v wl = wlo[i];
            g0 = fdot2(wih2[i], xh0[i], g0);
            g0 = fdot2(wih2[i], xl0[i], g0);
            g0 = fdot2(wl, xh0[i], g0);
            g1 = fdot2(wih2[i], xh1[i], g1);
            g1 = fdot2(wih2[i], xl1[i], g1);
            g1 = fdot2(wl, xh1[i], g1);
        }
        sGiP[hf][0][o] = g0;
        sGiP[hf][1][o] = g1;
    };
    auto do_gh = [&]() {
        float g0 = bhhv, g1 = 0.0f;
        const h2v* h0p = (const h2v*)&sH2[0][hf * 64];
        const h2v* h1p = (const h2v*)&sH2[1][hf * 64];
#pragma unroll
        for (int i = 0; i < 32; i++) {
            g0 = fdot2(whh2[i], h0p[i], g0);
            g1 = fdot2(whh2[i], h1p[i], g1);
        }
        sGhP[hf][0][o] = g0;
        sGhP[hf][1][o] = g1;
    };
    // wave 0; lane = x-output index; y delivered via in-wave shfl broadcast
    auto do_lift = [&](float4 u0, float4 u1, float yr) {
        float y00 = __shfl(yr, 0),  y01 = __shfl(yr, 1),  y02 = __shfl(yr, 2);
        float y03 = __shfl(yr, 3),  y04 = __shfl(yr, 4);
        float y10 = __shfl(yr, 16), y11 = __shfl(yr, 17), y12 = __shfl(yr, 18);
        float y13 = __shfl(yr, 19), y14 = __shfl(yr, 20);
        const float* wl = &sWlift[lane * 9];
        float bl = sblift[lane];
        float a0 = bl, a1 = bl;
        a0 = fmaf(wl[0], u0.x, a0);   a1 = fmaf(wl[0], u1.x, a1);
        a0 = fmaf(wl[1], u0.y, a0);   a1 = fmaf(wl[1], u1.y, a1);
        a0 = fmaf(wl[2], u0.z, a0);   a1 = fmaf(wl[2], u1.z, a1);
        a0 = fmaf(wl[3], u0.w, a0);   a1 = fmaf(wl[3], u1.w, a1);
        a0 = fmaf(wl[4], y00, a0);    a1 = fmaf(wl[4], y10, a1);
        a0 = fmaf(wl[5], y01, a0);    a1 = fmaf(wl[5], y11, a1);
        a0 = fmaf(wl[6], y02, a0);    a1 = fmaf(wl[6], y12, a1);
        a0 = fmaf(wl[7], y03, a0);    a1 = fmaf(wl[7], y13, a1);
        a0 = fmaf(wl[8], y04, a0);    a1 = fmaf(wl[8], y14, a1);
        float x0 = a0 * sigf(a0), x1 = a1 * sigf(a1);   // silu fp32
        _Float16 xh0 = (_Float16)x0;
        sX2hi[0][lane] = xh0;
        sX2lo[0][lane] = (_Float16)(x0 - (float)xh0);
        _Float16 xh1 = (_Float16)x1;
        sX2hi[1][lane] = xh1;
        sX2lo[1][lane] = (_Float16)(x1 - (float)xh1);
    };

    // ---- prologue: lift(0), gi(0) ----
    if (wid == 0) {
        float4 u0 = *(const float4*)&u_seq[((size_t)b0 * KST) * 4];
        float4 u1 = *(const float4*)&u_seq[((size_t)(b0 + 1) * KST) * 4];
        do_lift(u0, u1, yreg);
    }
    __syncthreads();
    do_gi();
    __syncthreads();

    for (int k = 0; k < KST; k++) {
        // ---------- Ψ1: gates(k) ----------
        if (t < 256) {
            int r = t >> 7, q = t & 127;
            float ir  = sGiP[0][r][q]       + sGiP[1][r][q];
            float iz  = sGiP[0][r][q + 128] + sGiP[1][r][q + 128];
            float in_ = sGiP[0][r][q + 256] + sGiP[1][r][q + 256];
            float hr  = sGhP[0][r][q]       + sGhP[1][r][q];
            float hz  = sGhP[0][r][q + 128] + sGhP[1][r][q + 128];
            float hn  = sGhP[0][r][q + 256] + sGhP[1][r][q + 256];
            float rr = sigf(ir + hr);
            float z  = sigf(iz + hz);
            float n  = tanhfast(fmaf(rr, hn, in_));
            float h  = sH[r][q];
            float hnew = fmaf(z, h - n, n);
            sH[r][q] = hnew;
            sH2[r][q] = (_Float16)hnew;
        }
        __syncthreads();

        // ---------- Ψ2: gh(k+1) all waves; wave 0 also head -> M^10 -> lift ----------
        float4 ukr{}, un0{}, un1{};
        float dtr = 0.0f;
        if (wid == 0) {   // early global loads (L2-resident); latency hides under gh
            int kn = (k + 1 < KST) ? k + 1 : KST - 1;
            ukr = *(const float4*)&u_seq[((size_t)(b0 + rh) * KST + k) * 4];
            dtr = dt_seq[(size_t)(b0 + rh) * KST + k];
            un0 = *(const float4*)&u_seq[((size_t)b0 * KST + kn) * 4];
            un1 = *(const float4*)&u_seq[((size_t)(b0 + 1) * KST + kn) * 4];
        }
        do_gh();
        if (wid == 0) {
            // ----- head: lane = hh*32 + rh*16 + oo; exact v11 summation tree -----
            const int hh = (lane >> 5) & 1;
            const int oo = lane & 15;
            float accv[4] = {0.f, 0.f, 0.f, 0.f};
            if (oo < 13) {
                const float4* wv = (const float4*)&sWheadP[oo * 132 + hh * 64];
                const float4* hv = (const float4*)&sH[rh][hh * 64];
#pragma unroll
                for (int c = 0; c < 4; c++) {
                    float4 w0 = wv[4 * c], w1 = wv[4 * c + 1], w2 = wv[4 * c + 2], w3 = wv[4 * c + 3];
                    float4 h0 = hv[4 * c], h1 = hv[4 * c + 1], h2 = hv[4 * c + 2], h3 = hv[4 * c + 3];
                    float a0 = w0.x * h0.x, a1 = w2.x * h2.x;
                    a0 = fmaf(w0.y, h0.y, a0); a1 = fmaf(w2.y, h2.y, a1);
                    a0 = fmaf(w0.z, h0.z, a0); a1 = fmaf(w2.z, h2.z, a1);
                    a0 = fmaf(w0.w, h0.w, a0); a1 = fmaf(w2.w, h2.w, a1);
                    a0 = fmaf(w1.x, h1.x, a0); a1 = fmaf(w3.x, h3.x, a1);
                    a0 = fmaf(w1.y, h1.y, a0); a1 = fmaf(w3.y, h3.y, a1);
                    a0 = fmaf(w1.z, h1.z, a0); a1 = fmaf(w3.z, h3.z, a1);
                    a0 = fmaf(w1.w, h1.w, a0); a1 = fmaf(w3.w, h3.w, a1);
                    accv[c] = a0 + a1;
                }
            }
            float p1 = accv[0] + accv[1];
            float p2 = accv[2] + accv[3];
            float part = p1 + p2;                       // ((s0+s1)+(s2+s3))
            float tot = part + __shfl_xor(part, 32);    // + ((s4+s5)+(s6+s7))
            float gval = 0.0f;
            if (oo < 13 && hh == 0) {
                float raw = tot + sbhead[oo];
                if (oo < 8) {
                    gval = fmaf(2.99f, sigf(raw), 0.01f);
                    out[OFF_R + ((size_t)(b0 + rh) * KST + k) * 8 + oo] = gval;
                } else {
                    gval = 3.0f * sigf(raw);
                    out[OFF_D + ((size_t)(b0 + rh) * KST + k) * 5 + (oo - 8)] = gval;
                }
            }

            // ----- y_jump on M lanes (all data via in-wave shfl) -----
            float u0x = __shfl(ukr.x, mr * 16), u0y = __shfl(ukr.y, mr * 16);
            float u0z = __shfl(ukr.z, mr * 16), u0w = __shfl(ukr.w, mr * 16);
            float dtv = __shfl(dtr, mr * 16);
            float dhj = __shfl(gval, mr * 16 + 8 + mj);
            float yj  = __shfl(yreg, mr * 16 + mj);
            float jmp = u0x * sU2Y[mj];
            jmp = fmaf(u0y, sU2Y[5 + mj], jmp);
            jmp = fmaf(u0z, sU2Y[10 + mj], jmp);
            jmp = fmaf(u0w, sU2Y[15 + mj], jmp);
            float yjv = yj + jmp + dhj;

            // ----- build M (one RK4 substep, exact; v12-proven) -----
            float kf1 = __shfl(gval, mr * 16 + 0);
            float kf2 = __shfl(gval, mr * 16 + 1);
            float kf3 = __shfl(gval, mr * 16 + 2);
            float kf4 = __shfl(gval, mr * 16 + 3);
            float kr1 = __shfl(gval, mr * 16 + 4);
            float kr2 = __shfl(gval, mr * 16 + 5);
            float kr3 = __shfl(gval, mr * 16 + 6);
            float kr4 = __shfl(gval, mr * 16 + 7);
            const float hstep = dtv * 0.1f;
            const float d1 = kr1 + kf2, d2 = kr2 + kf3, d3 = kr3 + kf4;
            float v0 = (mj == 0) ? 1.f : 0.f;
            float v1 = (mj == 1) ? 1.f : 0.f;
            float v2 = (mj == 2) ? 1.f : 0.f;
            float v3 = (mj == 3) ? 1.f : 0.f;
            float v4 = (mj == 4) ? 1.f : 0.f;
            float a0 = v0, a1 = v1, a2 = v2, a3 = v3, a4 = v4;
#pragma unroll
            for (int s = 1; s <= 4; s++) {
                const float hsf = hstep * ((s == 1) ? 1.0f : (s == 2) ? 0.5f
                                          : (s == 3) ? (1.0f / 3.0f) : 0.25f);
                float t0 = kr1 * v1 - kf1 * v0;
                float t1 = fmaf(kf1, v0, fmaf(kr2, v2, -d1 * v1));
                float t2 = fmaf(kf2, v1, fmaf(kr3, v3, -d2 * v2));
                float t3 = fmaf(kf3, v2, fmaf(kr4, v4, -d3 * v3));
                float t4 = kf4 * v3 - kr4 * v4;
                v0 = t0 * hsf; v1 = t1 * hsf; v2 = t2 * hsf; v3 = t3 * hsf; v4 = t4 * hsf;
                a0 += v0; a1 += v1; a2 += v2; a3 += v3; a4 += v4;
            }
            float m = a0;
            m = (mi == 1) ? a1 : m;
            m = (mi == 2) ? a2 : m;
            m = (mi == 3) ? a3 : m;
            m = (mi == 4) ? a4 : m;

            // ----- M^10 = ((M^2)^2 * M)^2 via lane-parallel 5x5 matmuls -----
            auto matmul = [&](float A, float B) -> float {
                float c = 0.0f;
#pragma unroll
                for (int kk = 0; kk < 5; kk++) {
                    float av = __shfl(A, rowBase + kk);
                    float bv = __shfl(B, colBase + 5 * kk);
                    c = fmaf(av, bv, c);
                }
                return c;
            };
            float m2  = matmul(m, m);
            float m4  = matmul(m2, m2);
            float m5  = matmul(m4, m);
            float m10 = matmul(m5, m5);

            // ----- y_out = M^10 * y_jump; clamp (no-op) kept for safety -----
            float p = m10 * yjv;
            float sum = __shfl(p, rowBase + 0);
            sum += __shfl(p, rowBase + 1);
            sum += __shfl(p, rowBase + 2);
            sum += __shfl(p, rowBase + 3);
            sum += __shfl(p, rowBase + 4);
            float ynew = fmaxf(sum, 0.0f);

            // scatter back to home layout (lane rh*16+i <- lane rh*32+i*5)
            yreg = __shfl(ynew, rh * 32 + ri * 5);
            if (lane < 32 && ri < 5)
                out[((size_t)(b0 + rh) * KST + k) * 5 + ri] = yreg;
            do_lift(un0, un1, yreg);                     // lift(k+1), y via shfl
        }
        __syncthreads();

        // ---------- Ψ3: gi(k+1) ----------
        do_gi();
        __syncthreads();
    }
}

}  // namespace

extern "C" void kernel_launch(void* const* d_in, const int* in_sizes, int n_in,
                              void* d_out, int out_size, void* d_ws, size_t ws_size,
                              hipStream_t stream) {
    const float* y0     = (const float*)d_in[0];
    const float* u_seq  = (const float*)d_in[1];
    const float* dt_seq = (const float*)d_in[2];
    const float* W_lift = (const float*)d_in[3];
    const float* b_lift = (const float*)d_in[4];
    const float* W_ih   = (const float*)d_in[5];
    const float* W_hh   = (const float*)d_in[6];
    const float* b_ih   = (const float*)d_in[7];
    const float* b_hh   = (const float*)d_in[8];
    const float* W_head = (const float*)d_in[9];
    const float* b_head = (const float*)d_in[10];
    const float* u2y    = (const float*)d_in[11];
    float* out = (float*)d_out;

    rnn_v18<<<256, 768, 0, stream>>>(y0, u_seq, dt_seq, W_lift, b_lift,
                                     W_ih, W_hh, b_ih, b_hh, W_head, b_head,
                                     u2y, out);
}